// Round 8
// baseline (12590.685 us; speedup 1.0000x reference)
//
#include <hip/hip_runtime.h>

constexpr int UNITS = 10;
constexpr int TIN = 50;
constexpr int TOUT = 3;
constexpr int G4 = 40;
constexpr int BLK = 256;

constexpr float NEG_LOG2E = -1.44269504088896341f;

typedef float floatx4 __attribute__((ext_vector_type(4)));

// ws layout (floats), all quad(16B)-aligned:
//   0    : R1s[10][40]  (400)  R1 row-major, col g scaled by s(g)= (g in [20,30))?1:-log2e
//   400  : W1s[40]      scaled
//   440  : b1s[40]      scaled
//   480  : W2s[10][40]  scaled cols
//   880  : b2s[40]      scaled
//   920  : R2q[10][10][4] (400)  R2q[u][v][ga] = R2[v*40+ga*10+u]*s(ga)  (round-7 layout, verified)
constexpr int WS_FLOATS = 1320;

__global__ void prep_weights(const float* __restrict__ W1, const float* __restrict__ R1,
                             const float* __restrict__ b1, const float* __restrict__ W2,
                             const float* __restrict__ R2, const float* __restrict__ b2,
                             float* __restrict__ ws)
{
    const int tid = threadIdx.x;
    for (int i = tid; i < 400; i += BLK) {
        const int col = i % G4;
        const float s = (col >= 20 && col < 30) ? 1.0f : NEG_LOG2E;
        ws[i]       = R1[i] * s;          // R1s: same layout, column-scaled
        ws[480 + i] = W2[i] * s;          // W2s
        const int u = i / 40, r = i % 40, v = r / 4, ga = r % 4;
        const float s3 = (ga == 2) ? 1.0f : NEG_LOG2E;
        ws[920 + i] = R2[v * G4 + ga * 10 + u] * s3;   // R2q
    }
    for (int i = tid; i < 40; i += BLK) {
        const float s = (i >= 20 && i < 30) ? 1.0f : NEG_LOG2E;
        ws[400 + i] = W1[i] * s;
        ws[440 + i] = b1[i] * s;
        ws[880 + i] = b2[i] * s;
    }
}

__device__ __forceinline__ float sig_pre(float zs) {
    // zs prescaled by -log2(e): sigmoid(z) = 1/(1+2^zs); v_exp_f32 computes 2^x
    return __builtin_amdgcn_rcpf(1.0f + __builtin_amdgcn_exp2f(zs));
}

__global__ __launch_bounds__(BLK, 4) void lstm_ae_kernel(
    const float* __restrict__ X, const float* __restrict__ ws,
    const float* __restrict__ Wd, const float* __restrict__ bd,
    float* __restrict__ out, int B)
{
    __shared__ __align__(16) float s[WS_FLOATS];     // 5.3 KB
    for (int i = threadIdx.x; i < WS_FLOATS; i += BLK) s[i] = ws[i];
    __syncthreads();

    const floatx4* __restrict__ R1q = (const floatx4*)(s);         // [u*10 + q]
    const floatx4* __restrict__ W1q = (const floatx4*)(s + 400);   // [q]
    const floatx4* __restrict__ b1q = (const floatx4*)(s + 440);   // [q]
    const float*   __restrict__ sW2 = s + 480;
    const floatx4* __restrict__ b2q = (const floatx4*)(s + 880);
    const float*   __restrict__ sR2 = s + 920;

    const int b = blockIdx.x * BLK + threadIdx.x;
    if (b >= B) return;

    // ---------------- LSTM 1: 50 steps, full z[40] live (round-4 schedule),
    // weights via ds_read_b128 quads (broadcast, offsets fold to immediates) --
    float h[UNITS], c[UNITS];
    #pragma unroll
    for (int u = 0; u < UNITS; ++u) { h[u] = 0.0f; c[u] = 0.0f; }

#define STEP(xval)                                                            \
    {                                                                         \
        const float x = (xval);                                               \
        float z[G4];                                                          \
        _Pragma("unroll")                                                     \
        for (int q = 0; q < 10; ++q) {                                        \
            const floatx4 wv = W1q[q], bv = b1q[q];                           \
            _Pragma("unroll")                                                 \
            for (int e = 0; e < 4; ++e) z[q * 4 + e] = fmaf(x, wv[e], bv[e]); \
        }                                                                     \
        _Pragma("unroll")                                                     \
        for (int u = 0; u < UNITS; ++u) {                                     \
            const float hu = h[u];                                            \
            _Pragma("unroll")                                                 \
            for (int q = 0; q < 10; ++q) {                                    \
                const floatx4 rv = R1q[u * 10 + q];                           \
                _Pragma("unroll")                                             \
                for (int e = 0; e < 4; ++e)                                   \
                    z[q * 4 + e] = fmaf(hu, rv[e], z[q * 4 + e]);             \
            }                                                                 \
        }                                                                     \
        _Pragma("unroll")                                                     \
        for (int u = 0; u < UNITS; ++u) {                                     \
            const float ig = sig_pre(z[u]);                                   \
            const float fg = sig_pre(z[10 + u]);                              \
            const float gg = fmaxf(z[20 + u], 0.0f);                          \
            const float og = sig_pre(z[30 + u]);                              \
            const float cn = fmaf(fg, c[u], ig * gg);                         \
            c[u] = cn;                                                        \
            h[u] = og * fmaxf(cn, 0.0f);                                      \
        }                                                                     \
    }

    // x: float2 loads, one pair-iteration of software prefetch
    const float2* __restrict__ xp = (const float2*)(X + (size_t)b * TIN);
    float2 xv = xp[0];
    #pragma unroll 1
    for (int p = 0; p < TIN / 2 - 1; ++p) {
        const float2 xn = xp[p + 1];
        STEP(xv.x)
        STEP(xv.y)
        xv = xn;
    }
    STEP(xv.x)
    STEP(xv.y)
#undef STEP

    // ---------------- RepeatVector(3) + LSTM 2 + Dense (all static) --------
    float xz[G4];
    #pragma unroll
    for (int q = 0; q < 10; ++q) {
        floatx4 a = b2q[q];
        #pragma unroll
        for (int u = 0; u < UNITS; ++u) {
            const floatx4 wv = *(const floatx4*)(sW2 + u * G4 + q * 4);
            const float hu = h[u];
            #pragma unroll
            for (int e = 0; e < 4; ++e) a[e] = fmaf(hu, wv[e], a[e]);
        }
        #pragma unroll
        for (int e = 0; e < 4; ++e) xz[q * 4 + e] = a[e];
    }

    const float bd0 = bd[0];
    float h2[UNITS], c2[UNITS], o0;
    {   // t2 = 0: h_prev = c_prev = 0
        float acc = bd0;
        #pragma unroll
        for (int u = 0; u < UNITS; ++u) {
            const float ig = sig_pre(xz[u]);
            const float gg = fmaxf(xz[20 + u], 0.0f);
            const float og = sig_pre(xz[30 + u]);
            const float cn = ig * gg;
            c2[u] = cn;
            const float hn = og * fmaxf(cn, 0.0f);
            h2[u] = hn;
            acc = fmaf(hn, Wd[u], acc);
        }
        o0 = acc;
    }

    float oacc[2];
    #pragma unroll
    for (int t2 = 0; t2 < 2; ++t2) {
        float hold[UNITS];
        #pragma unroll
        for (int u = 0; u < UNITS; ++u) hold[u] = h2[u];
        float acc = bd0;
        #pragma unroll
        for (int u = 0; u < UNITS; ++u) {
            float zi = xz[u];
            float zf = xz[10 + u];
            float zg = xz[20 + u];
            float zo = xz[30 + u];
            #pragma unroll
            for (int v = 0; v < UNITS; ++v) {
                const floatx4 rv = *(const floatx4*)(sR2 + u * G4 + v * 4);
                const float hv = hold[v];
                zi = fmaf(hv, rv[0], zi);
                zf = fmaf(hv, rv[1], zf);
                zg = fmaf(hv, rv[2], zg);
                zo = fmaf(hv, rv[3], zo);
            }
            const float ig = sig_pre(zi);
            const float fg = sig_pre(zf);
            const float gg = fmaxf(zg, 0.0f);
            const float og = sig_pre(zo);
            const float cn = fmaf(fg, c2[u], ig * gg);
            c2[u] = cn;
            const float hn = og * fmaxf(cn, 0.0f);
            h2[u] = hn;
            acc = fmaf(hn, Wd[u], acc);
        }
        oacc[t2] = acc;
    }

    float* __restrict__ o3 = out + (size_t)b * TOUT;
    o3[0] = o0;
    o3[1] = oacc[0];
    o3[2] = oacc[1];
}

extern "C" void kernel_launch(void* const* d_in, const int* in_sizes, int n_in,
                              void* d_out, int out_size, void* d_ws, size_t ws_size,
                              hipStream_t stream) {
    const float* X  = (const float*)d_in[0];
    const float* W1 = (const float*)d_in[1];
    const float* R1 = (const float*)d_in[2];
    const float* b1 = (const float*)d_in[3];
    const float* W2 = (const float*)d_in[4];
    const float* R2 = (const float*)d_in[5];
    const float* b2 = (const float*)d_in[6];
    const float* Wd = (const float*)d_in[7];
    const float* bd = (const float*)d_in[8];
    float* out = (float*)d_out;
    float* ws  = (float*)d_ws;

    const int B = in_sizes[0] / TIN;   // 524288
    prep_weights<<<1, BLK, 0, stream>>>(W1, R1, b1, W2, R2, b2, ws);
    const int grid = (B + BLK - 1) / BLK;   // 2048
    lstm_ae_kernel<<<grid, BLK, 0, stream>>>(X, ws, Wd, bd, out, B);
}

// Round 9
// 2212.068 us; speedup vs baseline: 5.6918x; 5.6918x over previous
//
#include <hip/hip_runtime.h>

constexpr int TIN = 50;
constexpr int BLK = 256;
constexpr float NEG_LOG2E = -1.44269504088896341f;

typedef float floatx4 __attribute__((ext_vector_type(4)));

// ws float layout (all offsets 16B-aligned). Gate-major, padded 10->12 per gate
// so every quad is single-gate. k = gate*12 + j, gate in {0:i,1:f,2:g,3:o}, j<10 real.
// i/f/o columns pre-scaled by -log2(e) so sigmoid(z) = rcp(1 + exp2(z')).
//   0    R1p[10][48]   (u = source unit)
//   480  W1p[48]
//   528  b1p[48]
//   576  W2p[10][48]
//   1056 b2p[48]
//   1104 R2p[10][48]
//   1584 Wdp[12]       (dense weights, pad 0)
// total 1596 floats = 6384 B
constexpr int WS_FLOATS = 1596;

__global__ void prep_weights(const float* __restrict__ W1, const float* __restrict__ R1,
                             const float* __restrict__ b1, const float* __restrict__ W2,
                             const float* __restrict__ R2, const float* __restrict__ b2,
                             const float* __restrict__ Wd, float* __restrict__ ws)
{
    const int tid = threadIdx.x;
    for (int i = tid; i < 480; i += BLK) {
        const int u = i / 48, k = i % 48, gate = k / 12, j = k % 12;
        const float sg = (gate == 2) ? 1.0f : NEG_LOG2E;
        ws[i]        = (j < 10) ? R1[u * 40 + gate * 10 + j] * sg : 0.0f;
        ws[576 + i]  = (j < 10) ? W2[u * 40 + gate * 10 + j] * sg : 0.0f;
        ws[1104 + i] = (j < 10) ? R2[u * 40 + gate * 10 + j] * sg : 0.0f;
    }
    for (int k = tid; k < 48; k += BLK) {
        const int gate = k / 12, j = k % 12;
        const float sg = (gate == 2) ? 1.0f : NEG_LOG2E;
        ws[480 + k]  = (j < 10) ? W1[gate * 10 + j] * sg : 0.0f;
        ws[528 + k]  = (j < 10) ? b1[gate * 10 + j] * sg : 0.0f;
        ws[1056 + k] = (j < 10) ? b2[gate * 10 + j] * sg : 0.0f;
    }
    if (tid < 12) ws[1584 + tid] = (tid < 10) ? Wd[tid] : 0.0f;
}

#define EFMA __builtin_elementwise_fma
#define EMAX __builtin_elementwise_max

// sigmoid on a quad (inputs pre-scaled by -log2e): rcp(1 + exp2(z'))
#define SIGQ(dst, src)                                                        \
    dst[0] = __builtin_amdgcn_rcpf(1.0f + __builtin_amdgcn_exp2f((src)[0]));  \
    dst[1] = __builtin_amdgcn_rcpf(1.0f + __builtin_amdgcn_exp2f((src)[1]));  \
    dst[2] = __builtin_amdgcn_rcpf(1.0f + __builtin_amdgcn_exp2f((src)[2]));  \
    dst[3] = __builtin_amdgcn_rcpf(1.0f + __builtin_amdgcn_exp2f((src)[3]));

// LSTM cell update on one quad column: c = f*c + i*g ; h = o*relu(c)
#define ACTG(zi, zf, zg, zo, cq, hq)                                          \
    {   floatx4 pi_, pf_, po_;                                                \
        SIGQ(pi_, zi) SIGQ(pf_, zf) SIGQ(po_, zo)                             \
        const floatx4 pg_ = EMAX(zg, zero4);                                  \
        cq = EFMA(pf_, cq, pi_ * pg_);                                        \
        hq = po_ * EMAX(cq, zero4); }

// first-step variant (c_prev = 0): c = i*g
#define ACT0G(zi, zg, zo, cq, hq)                                             \
    {   floatx4 pi_, po_;                                                     \
        SIGQ(pi_, zi) SIGQ(po_, zo)                                           \
        const floatx4 pg_ = EMAX(zg, zero4);                                  \
        cq = pi_ * pg_;                                                       \
        hq = po_ * EMAX(cq, zero4); }

// scalar h[u] from 3 quads, u literal -> folds at compile time
#define QGET(q0, q1, q2, u)                                                   \
    ((u) < 4 ? (q0)[(u) & 3] : (u) < 8 ? (q1)[(u) & 3] : (q2)[(u) & 3])

#define ACCU(u)                                                               \
    {   const float hu_ = QGET(hq0, hq1, hq2, u);                             \
        const floatx4 hs_ = {hu_, hu_, hu_, hu_};                             \
        const floatx4* Rr_ = Rq_ + (u) * 12;                                  \
        zi0 = EFMA(hs_, Rr_[0],  zi0);  zi1 = EFMA(hs_, Rr_[1],  zi1);        \
        zi2 = EFMA(hs_, Rr_[2],  zi2);  zf0 = EFMA(hs_, Rr_[3],  zf0);        \
        zf1 = EFMA(hs_, Rr_[4],  zf1);  zf2 = EFMA(hs_, Rr_[5],  zf2);        \
        zg0 = EFMA(hs_, Rr_[6],  zg0);  zg1 = EFMA(hs_, Rr_[7],  zg1);        \
        zg2 = EFMA(hs_, Rr_[8],  zg2);  zo0 = EFMA(hs_, Rr_[9],  zo0);        \
        zo1 = EFMA(hs_, Rr_[10], zo1);  zo2 = EFMA(hs_, Rr_[11], zo2); }

// One LSTM1 step. Weight base laundered through empty asm each step so LICM
// cannot hoist the 120 loop-invariant quad loads into registers (spill bomb).
#define STEP(xval)                                                            \
    {   const float* wsl_ = ws;                                               \
        asm volatile("" : "+s"(wsl_));                                        \
        const floatx4* Rq_ = (const floatx4*)(wsl_);                          \
        const floatx4* Wq_ = (const floatx4*)(wsl_ + 480);                    \
        const floatx4* Bq_ = (const floatx4*)(wsl_ + 528);                    \
        const float x_ = (xval);                                              \
        const floatx4 xs_ = {x_, x_, x_, x_};                                 \
        floatx4 zi0 = EFMA(xs_, Wq_[0],  Bq_[0]);                             \
        floatx4 zi1 = EFMA(xs_, Wq_[1],  Bq_[1]);                             \
        floatx4 zi2 = EFMA(xs_, Wq_[2],  Bq_[2]);                             \
        floatx4 zf0 = EFMA(xs_, Wq_[3],  Bq_[3]);                             \
        floatx4 zf1 = EFMA(xs_, Wq_[4],  Bq_[4]);                             \
        floatx4 zf2 = EFMA(xs_, Wq_[5],  Bq_[5]);                             \
        floatx4 zg0 = EFMA(xs_, Wq_[6],  Bq_[6]);                             \
        floatx4 zg1 = EFMA(xs_, Wq_[7],  Bq_[7]);                             \
        floatx4 zg2 = EFMA(xs_, Wq_[8],  Bq_[8]);                             \
        floatx4 zo0 = EFMA(xs_, Wq_[9],  Bq_[9]);                             \
        floatx4 zo1 = EFMA(xs_, Wq_[10], Bq_[10]);                            \
        floatx4 zo2 = EFMA(xs_, Wq_[11], Bq_[11]);                            \
        ACCU(0) ACCU(1) ACCU(2) ACCU(3) ACCU(4)                               \
        ACCU(5) ACCU(6) ACCU(7) ACCU(8) ACCU(9)                               \
        ACTG(zi0, zf0, zg0, zo0, cq0, hq0)                                    \
        ACTG(zi1, zf1, zg1, zo1, cq1, hq1)                                    \
        ACTG(zi2, zf2, zg2, zo2, cq2, hq2)                                    \
    }

#define ACCW(u)                                                               \
    {   const float hu_ = QGET(hq0, hq1, hq2, u);                             \
        const floatx4 hs_ = {hu_, hu_, hu_, hu_};                             \
        const floatx4* Wr_ = W2q + (u) * 12;                                  \
        xq0 = EFMA(hs_, Wr_[0],  xq0);  xq1 = EFMA(hs_, Wr_[1],  xq1);        \
        xq2 = EFMA(hs_, Wr_[2],  xq2);  xq3 = EFMA(hs_, Wr_[3],  xq3);        \
        xq4 = EFMA(hs_, Wr_[4],  xq4);  xq5 = EFMA(hs_, Wr_[5],  xq5);        \
        xq6 = EFMA(hs_, Wr_[6],  xq6);  xq7 = EFMA(hs_, Wr_[7],  xq7);        \
        xq8 = EFMA(hs_, Wr_[8],  xq8);  xq9 = EFMA(hs_, Wr_[9],  xq9);        \
        xq10 = EFMA(hs_, Wr_[10], xq10); xq11 = EFMA(hs_, Wr_[11], xq11); }

#define ACC2(u)                                                               \
    {   const float hu_ = QGET(h2q0, h2q1, h2q2, u);                          \
        const floatx4 hs_ = {hu_, hu_, hu_, hu_};                             \
        const floatx4* Rr_ = R2q + (u) * 12;                                  \
        ti0 = EFMA(hs_, Rr_[0],  ti0);  ti1 = EFMA(hs_, Rr_[1],  ti1);        \
        ti2 = EFMA(hs_, Rr_[2],  ti2);  tf0 = EFMA(hs_, Rr_[3],  tf0);        \
        tf1 = EFMA(hs_, Rr_[4],  tf1);  tf2 = EFMA(hs_, Rr_[5],  tf2);        \
        tg0 = EFMA(hs_, Rr_[6],  tg0);  tg1 = EFMA(hs_, Rr_[7],  tg1);        \
        tg2 = EFMA(hs_, Rr_[8],  tg2);  to0 = EFMA(hs_, Rr_[9],  to0);        \
        to1 = EFMA(hs_, Rr_[10], to1);  to2 = EFMA(hs_, Rr_[11], to2); }

#define STEP2                                                                 \
    {   floatx4 ti0 = xq0, ti1 = xq1, ti2 = xq2;                              \
        floatx4 tf0 = xq3, tf1 = xq4, tf2 = xq5;                              \
        floatx4 tg0 = xq6, tg1 = xq7, tg2 = xq8;                              \
        floatx4 to0 = xq9, to1 = xq10, to2 = xq11;                            \
        ACC2(0) ACC2(1) ACC2(2) ACC2(3) ACC2(4)                               \
        ACC2(5) ACC2(6) ACC2(7) ACC2(8) ACC2(9)                               \
        ACTG(ti0, tf0, tg0, to0, c2q0, h2q0)                                  \
        ACTG(ti1, tf1, tg1, to1, c2q1, h2q1)                                  \
        ACTG(ti2, tf2, tg2, to2, c2q2, h2q2) }

#define DOUT(dst)                                                             \
    {   floatx4 dv_ = h2q0 * Wdq[0];                                          \
        dv_ = EFMA(h2q1, Wdq[1], dv_);                                        \
        dv_ = EFMA(h2q2, Wdq[2], dv_);                                        \
        dst = dv_[0] + dv_[1] + dv_[2] + dv_[3] + bd0; }

__global__ __launch_bounds__(BLK) __attribute__((amdgpu_waves_per_eu(4, 4)))
void lstm_ae_kernel(const float* __restrict__ X, const float* __restrict__ ws,
                    const float* __restrict__ bd, float* __restrict__ out, int B)
{
    const int b = blockIdx.x * BLK + threadIdx.x;
    if (b >= B) return;

    const floatx4 zero4 = {0.0f, 0.0f, 0.0f, 0.0f};

    // ---------------- LSTM 1: 50 steps, all state in named quads ----------
    floatx4 hq0 = zero4, hq1 = zero4, hq2 = zero4;
    floatx4 cq0 = zero4, cq1 = zero4, cq2 = zero4;

    const float2* __restrict__ xp = (const float2*)(X + (size_t)b * TIN);
    float2 xv = xp[0];
    #pragma unroll 1
    for (int p = 0; p < TIN / 2 - 1; ++p) {
        const float2 xn = xp[p + 1];
        STEP(xv.x)
        STEP(xv.y)
        xv = xn;
    }
    STEP(xv.x)
    STEP(xv.y)

    // ---------------- RepeatVector(3) + LSTM 2 + Dense --------------------
    const floatx4* __restrict__ W2q = (const floatx4*)(ws + 576);
    const floatx4* __restrict__ B2q = (const floatx4*)(ws + 1056);
    const floatx4* __restrict__ R2q = (const floatx4*)(ws + 1104);
    const floatx4* __restrict__ Wdq = (const floatx4*)(ws + 1584);
    const float bd0 = bd[0];

    // xz = h @ W2p + b2p (same input every repeated step)
    floatx4 xq0 = B2q[0], xq1 = B2q[1], xq2  = B2q[2],  xq3  = B2q[3];
    floatx4 xq4 = B2q[4], xq5 = B2q[5], xq6  = B2q[6],  xq7  = B2q[7];
    floatx4 xq8 = B2q[8], xq9 = B2q[9], xq10 = B2q[10], xq11 = B2q[11];
    ACCW(0) ACCW(1) ACCW(2) ACCW(3) ACCW(4)
    ACCW(5) ACCW(6) ACCW(7) ACCW(8) ACCW(9)

    floatx4 h2q0, h2q1, h2q2, c2q0, c2q1, c2q2;
    // t2 = 0: h_prev = c_prev = 0
    ACT0G(xq0, xq6, xq9,  c2q0, h2q0)
    ACT0G(xq1, xq7, xq10, c2q1, h2q1)
    ACT0G(xq2, xq8, xq11, c2q2, h2q2)
    float o0; DOUT(o0)
    // t2 = 1, 2
    float o1; STEP2 DOUT(o1)
    float o2; STEP2 DOUT(o2)

    float* __restrict__ o3 = out + (size_t)b * 3;
    o3[0] = o0;
    o3[1] = o1;
    o3[2] = o2;
}

extern "C" void kernel_launch(void* const* d_in, const int* in_sizes, int n_in,
                              void* d_out, int out_size, void* d_ws, size_t ws_size,
                              hipStream_t stream) {
    const float* X  = (const float*)d_in[0];
    const float* W1 = (const float*)d_in[1];
    const float* R1 = (const float*)d_in[2];
    const float* b1 = (const float*)d_in[3];
    const float* W2 = (const float*)d_in[4];
    const float* R2 = (const float*)d_in[5];
    const float* b2 = (const float*)d_in[6];
    const float* Wd = (const float*)d_in[7];
    const float* bd = (const float*)d_in[8];
    float* out = (float*)d_out;
    float* ws  = (float*)d_ws;

    const int B = in_sizes[0] / TIN;   // 524288
    prep_weights<<<1, BLK, 0, stream>>>(W1, R1, b1, W2, R2, b2, Wd, ws);
    const int grid = (B + BLK - 1) / BLK;   // 2048
    lstm_ae_kernel<<<grid, BLK, 0, stream>>>(X, ws, bd, out, B);
}

// Round 10
// 519.739 us; speedup vs baseline: 24.2250x; 4.2561x over previous
//
#include <hip/hip_runtime.h>

constexpr int TIN = 50;
constexpr int BLK = 256;
constexpr float NEG_LOG2E = -1.44269504088896341f;

typedef float floatx4 __attribute__((ext_vector_type(4)));

// ws float layout (16B-aligned, gate-major, 10->12 pad so quads are single-gate).
// k = gate*12 + j, gate {0:i,1:f,2:g,3:o}; i/f/o cols pre-scaled by -log2(e)
// so sigmoid(z) = rcp(1 + exp2(z')).
//   0    R1p[10][48]
//   480  W1p[48]
//   528  b1p[48]
//   576  W2p[10][48]
//   1056 b2p[48]
//   1104 R2p[10][48]
//   1584 Wdp[12]
constexpr int WS_FLOATS = 1596;

__global__ void prep_weights(const float* __restrict__ W1, const float* __restrict__ R1,
                             const float* __restrict__ b1, const float* __restrict__ W2,
                             const float* __restrict__ R2, const float* __restrict__ b2,
                             const float* __restrict__ Wd, float* __restrict__ ws)
{
    const int tid = threadIdx.x;
    for (int i = tid; i < 480; i += BLK) {
        const int u = i / 48, k = i % 48, gate = k / 12, j = k % 12;
        const float sg = (gate == 2) ? 1.0f : NEG_LOG2E;
        ws[i]        = (j < 10) ? R1[u * 40 + gate * 10 + j] * sg : 0.0f;
        ws[576 + i]  = (j < 10) ? W2[u * 40 + gate * 10 + j] * sg : 0.0f;
        ws[1104 + i] = (j < 10) ? R2[u * 40 + gate * 10 + j] * sg : 0.0f;
    }
    for (int k = tid; k < 48; k += BLK) {
        const int gate = k / 12, j = k % 12;
        const float sg = (gate == 2) ? 1.0f : NEG_LOG2E;
        ws[480 + k]  = (j < 10) ? W1[gate * 10 + j] * sg : 0.0f;
        ws[528 + k]  = (j < 10) ? b1[gate * 10 + j] * sg : 0.0f;
        ws[1056 + k] = (j < 10) ? b2[gate * 10 + j] * sg : 0.0f;
    }
    if (tid < 12) ws[1584 + tid] = (tid < 10) ? Wd[tid] : 0.0f;
}

#define EFMA __builtin_elementwise_fma
#define EMAX __builtin_elementwise_max
#define SB   __builtin_amdgcn_sched_barrier(0);

#define SIGQ(dst, src)                                                        \
    dst[0] = __builtin_amdgcn_rcpf(1.0f + __builtin_amdgcn_exp2f((src)[0]));  \
    dst[1] = __builtin_amdgcn_rcpf(1.0f + __builtin_amdgcn_exp2f((src)[1]));  \
    dst[2] = __builtin_amdgcn_rcpf(1.0f + __builtin_amdgcn_exp2f((src)[2]));  \
    dst[3] = __builtin_amdgcn_rcpf(1.0f + __builtin_amdgcn_exp2f((src)[3]));

#define SIG3(d0, d1, d2, s0, s1, s2) SIGQ(d0, s0) SIGQ(d1, s1) SIGQ(d2, s2)

// t{0,1,2} += HV * RB[u*12 + g*3 + {0,1,2}]   (one source unit, one gate)
#define RECQ(RB, g, u, HV, t0, t1, t2)                                        \
    {   const float h_ = (HV);                                                \
        const floatx4 hs_ = {h_, h_, h_, h_};                                 \
        t0 = EFMA(hs_, RB[(u) * 12 + (g) * 3 + 0], t0);                       \
        t1 = EFMA(hs_, RB[(u) * 12 + (g) * 3 + 1], t1);                       \
        t2 = EFMA(hs_, RB[(u) * 12 + (g) * 3 + 2], t2); }

// full 10-unit recurrence for one gate; sched_barrier every 2 units bounds
// the number of in-flight ds_read_b128 results (<=6 quads transient)
#define REC10(RB, g, H0, H1, H2, t0, t1, t2)                                  \
    RECQ(RB, g, 0, (H0)[0], t0, t1, t2) RECQ(RB, g, 1, (H0)[1], t0, t1, t2) SB\
    RECQ(RB, g, 2, (H0)[2], t0, t1, t2) RECQ(RB, g, 3, (H0)[3], t0, t1, t2) SB\
    RECQ(RB, g, 4, (H1)[0], t0, t1, t2) RECQ(RB, g, 5, (H1)[1], t0, t1, t2) SB\
    RECQ(RB, g, 6, (H1)[2], t0, t1, t2) RECQ(RB, g, 7, (H1)[3], t0, t1, t2) SB\
    RECQ(RB, g, 8, (H2)[0], t0, t1, t2) RECQ(RB, g, 9, (H2)[1], t0, t1, t2) SB

// LSTM1 gate pre-activation: t = x*W1p[g] + b1p[g] + h @ R1p[:,g]
#define GATE1(g, t0, t1, t2)                                                  \
    t0 = EFMA(xs_, Wq_[(g) * 3 + 0], Bq_[(g) * 3 + 0]);                       \
    t1 = EFMA(xs_, Wq_[(g) * 3 + 1], Bq_[(g) * 3 + 1]);                       \
    t2 = EFMA(xs_, Wq_[(g) * 3 + 2], Bq_[(g) * 3 + 2]);                       \
    REC10(Rq_, g, hq0, hq1, hq2, t0, t1, t2)

// One LSTM1 step, gate-chunked g -> i -> f -> o. All state in named quads.
#define STEP(xval)                                                            \
    {   int lof_ = 0;                                                         \
        asm volatile("" : "+v"(lof_));    /* block LICM of invariant loads */ \
        const floatx4* Rq_ = (const floatx4*)(smem + lof_);                   \
        const floatx4* Wq_ = (const floatx4*)(smem + 480 + lof_);             \
        const floatx4* Bq_ = (const floatx4*)(smem + 528 + lof_);             \
        const float x_ = (xval);                                              \
        const floatx4 xs_ = {x_, x_, x_, x_};                                 \
        floatx4 t0, t1, t2, p0, p1, p2, q0, q1, q2;                           \
        GATE1(2, t0, t1, t2)   /* g: relu */                                  \
        p0 = EMAX(t0, zero4); p1 = EMAX(t1, zero4); p2 = EMAX(t2, zero4); SB  \
        GATE1(0, t0, t1, t2)   /* i */                                        \
        SIG3(q0, q1, q2, t0, t1, t2)                                          \
        p0 *= q0; p1 *= q1; p2 *= q2; SB                                      \
        GATE1(1, t0, t1, t2)   /* f */                                        \
        SIG3(q0, q1, q2, t0, t1, t2)                                          \
        cq0 = EFMA(q0, cq0, p0); cq1 = EFMA(q1, cq1, p1);                     \
        cq2 = EFMA(q2, cq2, p2); SB                                           \
        GATE1(3, t0, t1, t2)   /* o (dot uses old h; h written after) */      \
        SIG3(q0, q1, q2, t0, t1, t2)                                          \
        hq0 = q0 * EMAX(cq0, zero4); hq1 = q1 * EMAX(cq1, zero4);             \
        hq2 = q2 * EMAX(cq2, zero4); SB                                       \
    }

// xz gate construction: xq = b2p[g] + h1 @ W2p[:,g]
#define XZG(g, x0, x1, x2)                                                    \
    x0 = B2q_[(g) * 3 + 0]; x1 = B2q_[(g) * 3 + 1]; x2 = B2q_[(g) * 3 + 2];   \
    REC10(W2q_, g, hq0, hq1, hq2, x0, x1, x2)

// LSTM2 gate pre-activation for t2>=1: t = xz[g] + h2_old @ R2p[:,g]
#define GATE2(g, i0, i1, i2, t0, t1, t2)                                      \
    t0 = i0; t1 = i1; t2 = i2;                                                \
    REC10(R2q_, g, ho0, ho1, ho2, t0, t1, t2)

#define STEP2                                                                 \
    {   const floatx4 ho0 = h2q0, ho1 = h2q1, ho2 = h2q2;                     \
        floatx4 tt0, tt1, tt2, pp0, pp1, pp2, qq0, qq1, qq2;                  \
        GATE2(2, xqg0, xqg1, xqg2, tt0, tt1, tt2)                             \
        pp0 = EMAX(tt0, zero4); pp1 = EMAX(tt1, zero4);                       \
        pp2 = EMAX(tt2, zero4); SB                                            \
        GATE2(0, xqi0, xqi1, xqi2, tt0, tt1, tt2)                             \
        SIG3(qq0, qq1, qq2, tt0, tt1, tt2)                                    \
        pp0 *= qq0; pp1 *= qq1; pp2 *= qq2; SB                                \
        GATE2(1, xqf0, xqf1, xqf2, tt0, tt1, tt2)                             \
        SIG3(qq0, qq1, qq2, tt0, tt1, tt2)                                    \
        c2q0 = EFMA(qq0, c2q0, pp0); c2q1 = EFMA(qq1, c2q1, pp1);             \
        c2q2 = EFMA(qq2, c2q2, pp2); SB                                       \
        GATE2(3, xqo0, xqo1, xqo2, tt0, tt1, tt2)                             \
        SIG3(qq0, qq1, qq2, tt0, tt1, tt2)                                    \
        h2q0 = qq0 * EMAX(c2q0, zero4); h2q1 = qq1 * EMAX(c2q1, zero4);       \
        h2q2 = qq2 * EMAX(c2q2, zero4); SB                                    \
    }

#define DOUT(dst)                                                             \
    {   floatx4 dv_ = h2q0 * Wdq_[0];                                         \
        dv_ = EFMA(h2q1, Wdq_[1], dv_);                                       \
        dv_ = EFMA(h2q2, Wdq_[2], dv_);                                       \
        dst = dv_[0] + dv_[1] + dv_[2] + dv_[3] + bd0; }

__global__ __launch_bounds__(BLK, 4)
void lstm_ae_kernel(const float* __restrict__ X, const float* __restrict__ ws,
                    const float* __restrict__ bd, float* __restrict__ out, int B)
{
    __shared__ __align__(16) float smem[WS_FLOATS];    // 6.4 KB
    for (int i = threadIdx.x; i < WS_FLOATS; i += BLK) smem[i] = ws[i];
    __syncthreads();

    const int b = blockIdx.x * BLK + threadIdx.x;
    if (b >= B) return;

    const floatx4 zero4 = {0.0f, 0.0f, 0.0f, 0.0f};

    // ---------------- LSTM 1: 50 steps ----------------
    floatx4 hq0 = zero4, hq1 = zero4, hq2 = zero4;
    floatx4 cq0 = zero4, cq1 = zero4, cq2 = zero4;

    const float2* __restrict__ xp = (const float2*)(X + (size_t)b * TIN);
    float2 xv = xp[0];
    #pragma unroll 1
    for (int p = 0; p < TIN / 2 - 1; ++p) {
        const float2 xn = xp[p + 1];
        STEP(xv.x)
        STEP(xv.y)
        xv = xn;
    }
    STEP(xv.x)
    STEP(xv.y)

    // ---------------- RepeatVector(3) + LSTM 2 + Dense ----------------
    const floatx4* W2q_ = (const floatx4*)(smem + 576);
    const floatx4* B2q_ = (const floatx4*)(smem + 1056);
    const floatx4* R2q_ = (const floatx4*)(smem + 1104);
    const floatx4* Wdq_ = (const floatx4*)(smem + 1584);
    const float bd0 = bd[0];

    floatx4 xqi0, xqi1, xqi2, xqf0, xqf1, xqf2;
    floatx4 xqg0, xqg1, xqg2, xqo0, xqo1, xqo2;
    XZG(0, xqi0, xqi1, xqi2) SB
    XZG(1, xqf0, xqf1, xqf2) SB
    XZG(2, xqg0, xqg1, xqg2) SB
    XZG(3, xqo0, xqo1, xqo2) SB

    floatx4 c2q0, c2q1, c2q2, h2q0, h2q1, h2q2, q0, q1, q2, s0, s1, s2;
    // t2 = 0: h_prev = c_prev = 0 -> c = sig(i)*relu(g)
    SIG3(q0, q1, q2, xqi0, xqi1, xqi2)
    c2q0 = q0 * EMAX(xqg0, zero4);
    c2q1 = q1 * EMAX(xqg1, zero4);
    c2q2 = q2 * EMAX(xqg2, zero4);
    SIG3(s0, s1, s2, xqo0, xqo1, xqo2)
    h2q0 = s0 * EMAX(c2q0, zero4);
    h2q1 = s1 * EMAX(c2q1, zero4);
    h2q2 = s2 * EMAX(c2q2, zero4);
    float o0; DOUT(o0)
    float o1; STEP2 DOUT(o1)
    float o2; STEP2 DOUT(o2)

    float* __restrict__ o3 = out + (size_t)b * 3;
    o3[0] = o0;
    o3[1] = o1;
    o3[2] = o2;
}

extern "C" void kernel_launch(void* const* d_in, const int* in_sizes, int n_in,
                              void* d_out, int out_size, void* d_ws, size_t ws_size,
                              hipStream_t stream) {
    const float* X  = (const float*)d_in[0];
    const float* W1 = (const float*)d_in[1];
    const float* R1 = (const float*)d_in[2];
    const float* b1 = (const float*)d_in[3];
    const float* W2 = (const float*)d_in[4];
    const float* R2 = (const float*)d_in[5];
    const float* b2 = (const float*)d_in[6];
    const float* Wd = (const float*)d_in[7];
    const float* bd = (const float*)d_in[8];
    float* out = (float*)d_out;
    float* ws  = (float*)d_ws;

    const int B = in_sizes[0] / TIN;   // 524288
    prep_weights<<<1, BLK, 0, stream>>>(W1, R1, b1, W2, R2, b2, Wd, ws);
    const int grid = (B + BLK - 1) / BLK;   // 2048
    lstm_ae_kernel<<<grid, BLK, 0, stream>>>(X, ws, bd, out, B);
}